// Round 16
// baseline (1616.240 us; speedup 1.0000x reference)
//
#include <hip/hip_runtime.h>
#include <hip/hip_fp16.h>
#include <stdint.h>

// LSTM policy rollout. Round-11 sync structure (proven 1008-1028 us) with the
// f,i gate dots moved to the MATRIX pipe: v_mfma_f32_16x16x32_f16, A-fragments
// resident in AGPRs (inline-asm "a" class — MFMA is the one instruction that
// reads AGPRs directly, unlike v_dot2 per r14). K=4096 split 256/wave across
// 16 waves; per-wave 8 MFMAs/panel accumulate 16 rows x K-slice; partials
// combined via LDS with a fixed 16-way tree. c-gate stays on the proven
// VALU fdot2 + LDS-row path. Register budget: 64 AGPR (A) + 8 AGPR (acc)
// + ~50 arch < 128 @ 4 waves/SIMD -> no spill by construction.
// Layout notes: B is group-broadcast z (all 16 cols identical -> any n-map
// works); A,B filled with the SAME slot->column function so any shared HW
// k-map yields the correct dot; D map n=lane&15, m=(lane>>4)*4+reg (m89).

#define HID    4096
#define CTX    1024
#define NSTEPS 256
#define NBLK   256
#define TPB    1024
#define WAVES  16
#define HROWS  16
#define GROWS  48
#define NCH    8           // column chunks of 512 (c-gate path)

typedef _Float16 h2 __attribute__((ext_vector_type(2)));
typedef uint32_t u32x4v __attribute__((ext_vector_type(4)));
typedef float    f32x4v __attribute__((ext_vector_type(4)));

__device__ __forceinline__ float fdot2f(uint32_t a, uint32_t b, float c) {
#if __has_builtin(__builtin_amdgcn_fdot2)
  return __builtin_amdgcn_fdot2(__builtin_bit_cast(h2, a),
                                __builtin_bit_cast(h2, b), c, false);
#else
  h2 x = __builtin_bit_cast(h2, a), y = __builtin_bit_cast(h2, b);
  return c + (float)x[0]*(float)y[0] + (float)x[1]*(float)y[1];
#endif
}
__device__ __forceinline__ uint32_t pkf16(float x, float y) {
  h2 v; v[0] = (_Float16)x; v[1] = (_Float16)y;
  return __builtin_bit_cast(uint32_t, v);
}
__device__ __forceinline__ uint4 cvt8(const float* p) {
  return make_uint4(pkf16(p[0],p[1]), pkf16(p[2],p[3]),
                    pkf16(p[4],p[5]), pkf16(p[6],p[7]));
}
__device__ __forceinline__ float dot4(float acc, uint4 a, uint4 b) {
  acc = fdot2f(a.x, b.x, acc); acc = fdot2f(a.y, b.y, acc);
  acc = fdot2f(a.z, b.z, acc); acc = fdot2f(a.w, b.w, acc);
  return acc;
}
// Pin a 128-bit value into an AGPR quad (no code emitted).
__device__ __forceinline__ void pinA(u32x4v &v) {
  asm volatile("" : "+a"(v));
}
// MFMA with A from AGPR, B from VGPR, C/D accumulated in AGPR.
__device__ __forceinline__ f32x4v mfma16(const u32x4v a, const u32x4v b, f32x4v c) {
  asm("v_mfma_f32_16x16x32_f16 %0, %1, %2, %0" : "+a"(c) : "a"(a), "v"(b));
  return c;
}
// MALL-coherent tagged exchange (global).
__device__ __forceinline__ void stT(uint64_t* p, uint32_t payload, uint32_t tag) {
  const uint64_t v = ((uint64_t)tag << 32) | (uint64_t)payload;
  __hip_atomic_store(p, v, __ATOMIC_RELAXED, __HIP_MEMORY_SCOPE_AGENT);
}
__device__ __forceinline__ uint64_t ldT(const uint64_t* p) {
  return __hip_atomic_load(p, __ATOMIC_RELAXED, __HIP_MEMORY_SCOPE_AGENT);
}

__global__ __launch_bounds__(TPB)
void lstm(const float* __restrict__ ctx, const float* __restrict__ u,
          const float* __restrict__ l1w, const float* __restrict__ l1b,
          const float* __restrict__ Wf,  const float* __restrict__ Wfb,
          const float* __restrict__ Wi,  const float* __restrict__ Wib,
          const float* __restrict__ Wc,  const float* __restrict__ Wcb,
          const float* __restrict__ Wow, const float* __restrict__ Wob,
          uint64_t* __restrict__ hh0, uint64_t* __restrict__ hh1,
          uint64_t* __restrict__ part0, uint64_t* __restrict__ part1,
          float* __restrict__ out)
{
  __shared__ uint4 wlds[WAVES][HID/8];    // c-gate row per wave, 128 KB
  __shared__ uint4 zsh4[HID/8];           // z packed f16x2, 8 KB
  __shared__ float red[WAVES];
  __shared__ float partF[16][17];         // f-gate K-slice partials
  __shared__ float partI[16][17];         // i-gate K-slice partials
  __shared__ float pre_c[HROWS];
  __shared__ float cst[HROWS];
  __shared__ float bias[GROWS];
  __shared__ float wx[GROWS];             // column-4096 (x) weight per row
  __shared__ float x0sh, osh, ssh;

  const int tid  = threadIdx.x;
  const int b    = blockIdx.x;
  const int wv   = tid >> 6;
  const int lane = tid & 63;

  uint32_t* z32 = (uint32_t*)zsh4;
  for (int i = tid; i < HID/2; i += TPB) z32[i] = 0u;
  if (tid < HROWS) cst[tid] = 0.f;
  if (tid < GROWS) {
    int g = tid / HROWS, j = tid % HROWS;
    const float* bw = (g==0 ? Wfb : (g==1 ? Wib : Wcb));
    const float* gw = (g==0 ? Wf  : (g==1 ? Wi  : Wc ));
    bias[tid] = bw[b*HROWS + j];
    wx[tid]   = gw[(size_t)(b*HROWS + j)*4097 + 4096];
  }

  // per-row o-gate weight for this block's h rows (tid<16, wave 0)
  const float wolocal = (tid < HROWS) ? Wow[b*HROWS + tid] : 0.f;
  const float woxw = Wow[HID];
  const float wob0 = Wob[0];

  // ---- A-fragments for f,i panels (this wave's K-slice) -> AGPR quads ----
  // A slot (lane, reg-pair): row = lane&15, k = wv*256 + (lane>>4)*8 + mi*32 + j
  u32x4v ffr[8], ifr[8];
  {
    const int arow  = b*HROWS + (lane & 15);
    const int kbase = wv*256 + (lane >> 4)*8;
    const float* rfA = Wf + (size_t)arow*4097 + kbase;
    const float* riA = Wi + (size_t)arow*4097 + kbase;
    #pragma unroll
    for (int mi = 0; mi < 8; ++mi) {
      ffr[mi] = __builtin_bit_cast(u32x4v, cvt8(rfA + mi*32)); pinA(ffr[mi]);
      ifr[mi] = __builtin_bit_cast(u32x4v, cvt8(riA + mi*32)); pinA(ifr[mi]);
    }
  }
  // c-gate row (row b*16+wv of Wc) -> LDS
  {
    const float* rc = Wc + (size_t)(b*HROWS + wv)*4097;
    #pragma unroll
    for (int c = 0; c < NCH; ++c)
      wlds[wv][c*64 + lane] = cvt8(rc + c*512 + lane*8);
  }

  // x0 = l1_w . context + l1_b (identical in every block); CTX == TPB
  {
    float p = l1w[tid] * ctx[tid];
    #pragma unroll
    for (int off = 32; off; off >>= 1) p += __shfl_down(p, off, 64);
    __syncthreads();                 // covers zsh init + wlds + cst
    if (lane == 0) red[wv] = p;
    __syncthreads();
    if (tid == 0) {
      float ssum = 0.f;
      for (int w = 0; w < WAVES; ++w) ssum += red[w];
      x0sh = ssum + l1b[0];
    }
    __syncthreads();
  }
  float xcur = x0sh;
  float logp = 0.f;
  float ut = u[0];

  for (int t = 0; t < NSTEPS; ++t) {
    // ---- wave 0: issue o-partial loads early (checked after dots) ----
    const uint64_t* prd = (t & 1) ? part0 : part1;
    uint64_t pv0 = 0, pv1 = 0, pv2 = 0, pv3 = 0;
    if (wv == 0 && t > 0) {
      pv0 = ldT(&prd[lane*4+0]); pv1 = ldT(&prd[lane*4+1]);
      pv2 = ldT(&prd[lane*4+2]); pv3 = ldT(&prd[lane*4+3]);
    }

    // ---- f,i panels on the matrix pipe (K-slice 256 per wave) ----
    f32x4v accf = {0.f, 0.f, 0.f, 0.f};
    f32x4v acci = {0.f, 0.f, 0.f, 0.f};
    {
      const int zb2 = wv*128 + (lane >> 4)*4;   // z32 index of this group's 8 cols
      #pragma unroll
      for (int mi = 0; mi < 8; ++mi) {
        const u32x4v bz =
            __builtin_bit_cast(u32x4v, *(const uint4*)&z32[zb2 + mi*16]);
        accf = mfma16(ffr[mi], bz, accf);
        acci = mfma16(ifr[mi], bz, acci);
      }
    }

    // ---- c-gate dot on VALU from LDS row ----
    float a2 = 0.f;
    #pragma unroll
    for (int c = 0; c < NCH; ++c) {
      const uint4 zz = zsh4[c*64 + lane];
      const uint4 wl = wlds[wv][c*64 + lane];
      a2 = dot4(a2, wl, zz);
    }
    #pragma unroll
    for (int off = 32; off; off >>= 1) a2 += __shfl_down(a2, off, 64);

    // ---- wave 0: finish o (fixed tree, bit-identical in every block) ----
    if (wv == 0) {
      float ps = 0.f;
      if (t > 0) {
        const uint32_t tg = (uint32_t)t;
        while ((uint32_t)(pv0 >> 32) != tg) { __builtin_amdgcn_s_sleep(1); pv0 = ldT(&prd[lane*4+0]); }
        while ((uint32_t)(pv1 >> 32) != tg) { __builtin_amdgcn_s_sleep(1); pv1 = ldT(&prd[lane*4+1]); }
        while ((uint32_t)(pv2 >> 32) != tg) { __builtin_amdgcn_s_sleep(1); pv2 = ldT(&prd[lane*4+2]); }
        while ((uint32_t)(pv3 >> 32) != tg) { __builtin_amdgcn_s_sleep(1); pv3 = ldT(&prd[lane*4+3]); }
        const float q0 = __uint_as_float((uint32_t)pv0);
        const float q1 = __uint_as_float((uint32_t)pv1);
        const float q2 = __uint_as_float((uint32_t)pv2);
        const float q3 = __uint_as_float((uint32_t)pv3);
        ps = ((q0 + q1) + q2) + q3;
      }
      #pragma unroll
      for (int off = 32; off; off >>= 1) ps += __shfl_down(ps, off, 64);
      if (lane == 0) {
        const float opre = ps + woxw*xcur + wob0;
        const float o = 1.f / (1.f + expf(-opre));
        osh = o;
        ssh = (ut < o) ? 1.f : 0.f;
      }
    }
    if (lane == 0)
      pre_c[wv] = a2 + wx[32+wv]*xcur + bias[32+wv];
    // D col 0 lives in lanes 0,16,32,48: rows (lane>>4)*4 + reg
    if ((lane & 15) == 0) {
      const int g = lane >> 4;
      #pragma unroll
      for (int r = 0; r < 4; ++r) {
        partF[g*4+r][wv] = accf[r];
        partI[g*4+r][wv] = acci[r];
      }
    }
    __syncthreads();   // pre_c/partF/partI/osh/ssh visible to all

    // ---- h update; wave 0 publishes tagged h + partial (epoch t+1) ----
    const float o = osh;
    const float s = ssh;
    uint64_t* hwH = (t & 1) ? hh1 : hh0;
    uint64_t* pwF = (t & 1) ? part1 : part0;
    float hv = 0.f;
    if (tid < HROWS) {
      float sf = 0.f, si = 0.f;
      #pragma unroll
      for (int w = 0; w < WAVES; ++w) { sf += partF[tid][w]; si += partI[tid][w]; }
      const float pf = sf + wx[tid]*xcur + bias[tid];
      const float pi = si + wx[16+tid]*xcur + bias[16+tid];
      const float ff = 1.f / (1.f + expf(-pf));
      const float ii = 1.f / (1.f + expf(-pi));
      const float cc = tanhf(pre_c[tid]);
      const float cn = ff*cst[tid] + ii*cc;
      cst[tid] = cn;
      hv = o * tanhf(cn);
    }
    if (tid < 64) {
      // partial o-dot over this block's 16 h values (deterministic tree)
      float pp = wolocal * hv;      // zero for lanes 16-63
      #pragma unroll
      for (int off = 8; off; off >>= 1) pp += __shfl_down(pp, off, 64);
      const float he = __shfl(hv, 2*(tid&7),   64);
      const float ho = __shfl(hv, 2*(tid&7)+1, 64);
      if (tid < 8) stT(&hwH[b*8 + tid], pkf16(he, ho), (uint32_t)(t+1));
      if (tid == 0) stT(&pwF[b], __float_as_uint(pp), (uint32_t)(t+1));
    }
    if (b == 0 && tid == 0) {
      logp += (s != 0.f) ? logf(o) : logf(1.f - o);
      out[t] = s;
    }
    xcur = s;

    if (t + 1 < NSTEPS) {
      // ---- gather z(t): poll the tagged words directly (one round trip) ----
      const uint64_t* hr2 = (t & 1) ? hh1 : hh0;
      const uint32_t tg = (uint32_t)(t+1);
      uint64_t v0 = ldT(&hr2[tid]);
      uint64_t v1 = ldT(&hr2[tid + TPB]);
      while ((uint32_t)(v0 >> 32) != tg) {
        __builtin_amdgcn_s_sleep(1); v0 = ldT(&hr2[tid]);
      }
      while ((uint32_t)(v1 >> 32) != tg) {
        __builtin_amdgcn_s_sleep(1); v1 = ldT(&hr2[tid + TPB]);
      }
      z32[tid]       = (uint32_t)v0;
      z32[tid + TPB] = (uint32_t)v1;
      ut = u[t+1];
      __syncthreads();
    }
  }
  if (b == 0 && tid == 0) out[NSTEPS] = logp;
}

extern "C" void kernel_launch(void* const* d_in, const int* in_sizes, int n_in,
                              void* d_out, int out_size, void* d_ws, size_t ws_size,
                              hipStream_t stream) {
  const float* ctx = (const float*)d_in[0];
  const float* u   = (const float*)d_in[1];
  const float* l1w = (const float*)d_in[2];
  const float* l1b = (const float*)d_in[3];
  const float* Wf  = (const float*)d_in[4];
  const float* Wfb = (const float*)d_in[5];
  const float* Wi  = (const float*)d_in[6];
  const float* Wib = (const float*)d_in[7];
  const float* Wc  = (const float*)d_in[8];
  const float* Wcb = (const float*)d_in[9];
  const float* Wow = (const float*)d_in[10];
  const float* Wob = (const float*)d_in[11];
  float* out = (float*)d_out;

  char* ws = (char*)d_ws;
  uint64_t* part0 = (uint64_t*)(ws + 4096);            // 256*8B
  uint64_t* part1 = (uint64_t*)(ws + 8192);
  uint64_t* hh0   = (uint64_t*)(ws + 12288);           // 2048*8B = 16 KB
  uint64_t* hh1   = (uint64_t*)(ws + 12288 + 16384);
  // zero all tags each launch (epochs 1..256; 0 == invalid)
  (void)hipMemsetAsync(ws + 4096, 0, 40960, stream);

  lstm<<<NBLK, TPB, 0, stream>>>(ctx,u,l1w,l1b,Wf,Wfb,Wi,Wib,Wc,Wcb,Wow,Wob,
                                 hh0,hh1,part0,part1,out);
}

// Round 17
// 1031.642 us; speedup vs baseline: 1.5667x; 1.5667x over previous
//
#include <hip/hip_runtime.h>
#include <hip/hip_fp16.h>
#include <stdint.h>

// LSTM policy rollout — final kernel (round-11 structure, proven 1008-1028 us).
// 256 blocks x 1024 threads, 1 block/CU. Weights: 2 rows/wave in AGPRs
// (inline-asm "a" class, unspillable; 64 slots) + 1 row/wave in LDS (128 KB).
// Cross-block exchange: h (f16x2) and o-partials published as {epoch,payload}
// uint64 via RELAXED agent-scope atomics (MALL-coherent; no fences, no RMWs,
// no buffer_inv anywhere in the loop). Consumers poll the tag of the exact
// word they need -> flag wait + data load fused into ONE MALL round trip.
// Structural floor: 256 sequential steps x (VALU ~1.3us + MALL publish->
// observe ~1.3us + 2 barriers) ~= 1.0 ms. Attempts beyond this (r12 big-AGPR,
// r13 wave-aligned 1-barrier, r14 AGPR-sourced v_dot2, r16 MFMA panels) all
// regressed or failed to compile; see session journal.

#define HID    4096
#define CTX    1024
#define NSTEPS 256
#define NBLK   256
#define TPB    1024
#define WAVES  16
#define HROWS  16
#define GROWS  48
#define RPW    3           // rows per wave (2 AGPR + 1 LDS)
#define NCH    8           // column chunks of 512

typedef _Float16 h2 __attribute__((ext_vector_type(2)));

__device__ __forceinline__ float fdot2f(uint32_t a, uint32_t b, float c) {
#if __has_builtin(__builtin_amdgcn_fdot2)
  return __builtin_amdgcn_fdot2(__builtin_bit_cast(h2, a),
                                __builtin_bit_cast(h2, b), c, false);
#else
  h2 x = __builtin_bit_cast(h2, a), y = __builtin_bit_cast(h2, b);
  return c + (float)x[0]*(float)y[0] + (float)x[1]*(float)y[1];
#endif
}
__device__ __forceinline__ uint32_t pkf16(float x, float y) {
  h2 v; v[0] = (_Float16)x; v[1] = (_Float16)y;
  return __builtin_bit_cast(uint32_t, v);
}
__device__ __forceinline__ uint4 cvt8(const float* p) {
  return make_uint4(pkf16(p[0],p[1]), pkf16(p[2],p[3]),
                    pkf16(p[4],p[5]), pkf16(p[6],p[7]));
}
__device__ __forceinline__ float dot4(float acc, uint4 a, uint4 b) {
  acc = fdot2f(a.x, b.x, acc); acc = fdot2f(a.y, b.y, acc);
  acc = fdot2f(a.z, b.z, acc); acc = fdot2f(a.w, b.w, acc);
  return acc;
}
// AGPR residency (proven rounds 7-15).
__device__ __forceinline__ void agw(uint32_t &slot, uint32_t v) {
  asm volatile("v_accvgpr_write_b32 %0, %1" : "=a"(slot) : "v"(v));
}
__device__ __forceinline__ uint32_t agr(uint32_t slot) {
  uint32_t v;
  asm("v_accvgpr_read_b32 %0, %1" : "=v"(v) : "a"(slot));
  return v;
}
// MALL-coherent tagged exchange (global).
__device__ __forceinline__ void stT(uint64_t* p, uint32_t payload, uint32_t tag) {
  const uint64_t v = ((uint64_t)tag << 32) | (uint64_t)payload;
  __hip_atomic_store(p, v, __ATOMIC_RELAXED, __HIP_MEMORY_SCOPE_AGENT);
}
__device__ __forceinline__ uint64_t ldT(const uint64_t* p) {
  return __hip_atomic_load(p, __ATOMIC_RELAXED, __HIP_MEMORY_SCOPE_AGENT);
}

__global__ __launch_bounds__(TPB)
void lstm(const float* __restrict__ ctx, const float* __restrict__ u,
          const float* __restrict__ l1w, const float* __restrict__ l1b,
          const float* __restrict__ Wf,  const float* __restrict__ Wfb,
          const float* __restrict__ Wi,  const float* __restrict__ Wib,
          const float* __restrict__ Wc,  const float* __restrict__ Wcb,
          const float* __restrict__ Wow, const float* __restrict__ Wob,
          uint64_t* __restrict__ hh0, uint64_t* __restrict__ hh1,
          uint64_t* __restrict__ part0, uint64_t* __restrict__ part1,
          float* __restrict__ out)
{
  __shared__ uint4 wlds[WAVES][HID/8];    // 1 LDS row per wave, 128 KB
  __shared__ uint4 zsh4[HID/8];           // z packed f16x2, 8 KB
  __shared__ float red[WAVES];
  __shared__ float pre[GROWS];
  __shared__ float cst[HROWS];
  __shared__ float bias[GROWS];
  __shared__ float wx[GROWS];             // column-4096 (x) weight per row
  __shared__ float x0sh, osh, ssh;

  const int tid  = threadIdx.x;
  const int b    = blockIdx.x;
  const int wv   = tid >> 6;
  const int lane = tid & 63;

  uint32_t* z32 = (uint32_t*)zsh4;
  for (int i = tid; i < HID/2; i += TPB) z32[i] = 0u;
  if (tid < HROWS) cst[tid] = 0.f;
  if (tid < GROWS) {
    int g = tid / HROWS, j = tid % HROWS;
    const float* bw = (g==0 ? Wfb : (g==1 ? Wib : Wcb));
    const float* gw = (g==0 ? Wf  : (g==1 ? Wi  : Wc ));
    bias[tid] = bw[b*HROWS + j];
    wx[tid]   = gw[(size_t)(b*HROWS + j)*4097 + 4096];
  }

  // per-row o-gate weight for this block's h rows (tid<16, wave 0)
  const float wolocal = (tid < HROWS) ? Wow[b*HROWS + tid] : 0.f;
  const float woxw = Wow[HID];
  const float wob0 = Wob[0];

  // load + convert this wave's 3 gate rows: 2 -> AGPRs, 1 -> LDS
  uint32_t wreg[64];    // fully unrolled access only; lives in AGPRs
  {
    const int fl0 = wv*RPW;
    const int g0 = (fl0+0)/HROWS, j0 = (fl0+0)%HROWS;
    const int g1 = (fl0+1)/HROWS, j1 = (fl0+1)%HROWS;
    const int g2 = (fl0+2)/HROWS, j2 = (fl0+2)%HROWS;
    const float* r0 = (g0==0?Wf:(g0==1?Wi:Wc)) + (size_t)(b*HROWS+j0)*4097;
    const float* r1 = (g1==0?Wf:(g1==1?Wi:Wc)) + (size_t)(b*HROWS+j1)*4097;
    const float* r2 = (g2==0?Wf:(g2==1?Wi:Wc)) + (size_t)(b*HROWS+j2)*4097;
    #pragma unroll
    for (int c = 0; c < NCH; ++c) {
      const int col = c*512 + lane*8;
      const uint4 va = cvt8(r0 + col);
      agw(wreg[c*8+0], va.x); agw(wreg[c*8+1], va.y);
      agw(wreg[c*8+2], va.z); agw(wreg[c*8+3], va.w);
      const uint4 vb = cvt8(r1 + col);
      agw(wreg[c*8+4], vb.x); agw(wreg[c*8+5], vb.y);
      agw(wreg[c*8+6], vb.z); agw(wreg[c*8+7], vb.w);
      wlds[wv][c*64 + lane] = cvt8(r2 + col);
    }
  }

  // x0 = l1_w . context + l1_b (identical in every block); CTX == TPB
  {
    float p = l1w[tid] * ctx[tid];
    #pragma unroll
    for (int off = 32; off; off >>= 1) p += __shfl_down(p, off, 64);
    __syncthreads();                 // covers zsh init + wlds + cst
    if (lane == 0) red[wv] = p;
    __syncthreads();
    if (tid == 0) {
      float ssum = 0.f;
      for (int w = 0; w < WAVES; ++w) ssum += red[w];
      x0sh = ssum + l1b[0];
    }
    __syncthreads();
  }
  float xcur = x0sh;
  float logp = 0.f;
  float ut = u[0];

  for (int t = 0; t < NSTEPS; ++t) {
    // ---- wave 0: issue o-partial loads early (checked after dots) ----
    const uint64_t* prd = (t & 1) ? part0 : part1;
    uint64_t pv0 = 0, pv1 = 0, pv2 = 0, pv3 = 0;
    if (wv == 0 && t > 0) {
      pv0 = ldT(&prd[lane*4+0]); pv1 = ldT(&prd[lane*4+1]);
      pv2 = ldT(&prd[lane*4+2]); pv3 = ldT(&prd[lane*4+3]);
    }

    // ---- f/i/c gate dots from resident weights (AGPR + LDS) ----
    float a0 = 0.f, a1 = 0.f, a2 = 0.f;
    #pragma unroll
    for (int c = 0; c < NCH; ++c) {
      const uint4 zz = zsh4[c*64 + lane];
      const uint4 wl = wlds[wv][c*64 + lane];
      a0 = fdot2f(agr(wreg[c*8+0]), zz.x, a0);
      a0 = fdot2f(agr(wreg[c*8+1]), zz.y, a0);
      a0 = fdot2f(agr(wreg[c*8+2]), zz.z, a0);
      a0 = fdot2f(agr(wreg[c*8+3]), zz.w, a0);
      a1 = fdot2f(agr(wreg[c*8+4]), zz.x, a1);
      a1 = fdot2f(agr(wreg[c*8+5]), zz.y, a1);
      a1 = fdot2f(agr(wreg[c*8+6]), zz.z, a1);
      a1 = fdot2f(agr(wreg[c*8+7]), zz.w, a1);
      a2 = dot4(a2, wl, zz);
    }
    #pragma unroll
    for (int off = 32; off; off >>= 1) {
      a0 += __shfl_down(a0, off, 64);
      a1 += __shfl_down(a1, off, 64);
      a2 += __shfl_down(a2, off, 64);
    }

    // ---- wave 0: finish o (fixed tree, bit-identical in every block) ----
    if (wv == 0) {
      float ps = 0.f;
      if (t > 0) {
        const uint32_t tg = (uint32_t)t;
        while ((uint32_t)(pv0 >> 32) != tg) { __builtin_amdgcn_s_sleep(1); pv0 = ldT(&prd[lane*4+0]); }
        while ((uint32_t)(pv1 >> 32) != tg) { __builtin_amdgcn_s_sleep(1); pv1 = ldT(&prd[lane*4+1]); }
        while ((uint32_t)(pv2 >> 32) != tg) { __builtin_amdgcn_s_sleep(1); pv2 = ldT(&prd[lane*4+2]); }
        while ((uint32_t)(pv3 >> 32) != tg) { __builtin_amdgcn_s_sleep(1); pv3 = ldT(&prd[lane*4+3]); }
        const float q0 = __uint_as_float((uint32_t)pv0);
        const float q1 = __uint_as_float((uint32_t)pv1);
        const float q2 = __uint_as_float((uint32_t)pv2);
        const float q3 = __uint_as_float((uint32_t)pv3);
        ps = ((q0 + q1) + q2) + q3;
      }
      #pragma unroll
      for (int off = 32; off; off >>= 1) ps += __shfl_down(ps, off, 64);
      if (lane == 0) {
        const float opre = ps + woxw*xcur + wob0;
        const float o = 1.f / (1.f + expf(-opre));
        osh = o;
        ssh = (ut < o) ? 1.f : 0.f;
      }
    }
    if (lane == 0) {
      const int fl = wv*RPW;
      pre[fl+0] = a0 + wx[fl+0]*xcur + bias[fl+0];
      pre[fl+1] = a1 + wx[fl+1]*xcur + bias[fl+1];
      pre[fl+2] = a2 + wx[fl+2]*xcur + bias[fl+2];
    }
    __syncthreads();   // pre[] + osh/ssh visible to all

    // ---- h update; wave 0 publishes tagged h + partial (epoch t+1) ----
    const float o = osh;
    const float s = ssh;
    uint64_t* hwH = (t & 1) ? hh1 : hh0;
    uint64_t* pwF = (t & 1) ? part1 : part0;
    float hv = 0.f;
    if (tid < HROWS) {
      const float ff = 1.f / (1.f + expf(-pre[tid]));
      const float ii = 1.f / (1.f + expf(-pre[HROWS+tid]));
      const float cc = tanhf(pre[2*HROWS+tid]);
      const float cn = ff*cst[tid] + ii*cc;
      cst[tid] = cn;
      hv = o * tanhf(cn);
    }
    if (tid < 64) {
      // partial o-dot over this block's 16 h values (deterministic tree)
      float pp = wolocal * hv;      // zero for lanes 16-63
      #pragma unroll
      for (int off = 8; off; off >>= 1) pp += __shfl_down(pp, off, 64);
      const float he = __shfl(hv, 2*(tid&7),   64);
      const float ho = __shfl(hv, 2*(tid&7)+1, 64);
      if (tid < 8) stT(&hwH[b*8 + tid], pkf16(he, ho), (uint32_t)(t+1));
      if (tid == 0) stT(&pwF[b], __float_as_uint(pp), (uint32_t)(t+1));
    }
    if (b == 0 && tid == 0) {
      logp += (s != 0.f) ? logf(o) : logf(1.f - o);
      out[t] = s;
    }
    xcur = s;

    if (t + 1 < NSTEPS) {
      // ---- gather z(t): poll the tagged words directly (one round trip) ----
      const uint64_t* hr2 = (t & 1) ? hh1 : hh0;
      const uint32_t tg = (uint32_t)(t+1);
      uint64_t v0 = ldT(&hr2[tid]);
      uint64_t v1 = ldT(&hr2[tid + TPB]);
      while ((uint32_t)(v0 >> 32) != tg) {
        __builtin_amdgcn_s_sleep(1); v0 = ldT(&hr2[tid]);
      }
      while ((uint32_t)(v1 >> 32) != tg) {
        __builtin_amdgcn_s_sleep(1); v1 = ldT(&hr2[tid + TPB]);
      }
      z32[tid]       = (uint32_t)v0;
      z32[tid + TPB] = (uint32_t)v1;
      ut = u[t+1];
      __syncthreads();
    }
  }
  if (b == 0 && tid == 0) out[NSTEPS] = logp;
}

extern "C" void kernel_launch(void* const* d_in, const int* in_sizes, int n_in,
                              void* d_out, int out_size, void* d_ws, size_t ws_size,
                              hipStream_t stream) {
  const float* ctx = (const float*)d_in[0];
  const float* u   = (const float*)d_in[1];
  const float* l1w = (const float*)d_in[2];
  const float* l1b = (const float*)d_in[3];
  const float* Wf  = (const float*)d_in[4];
  const float* Wfb = (const float*)d_in[5];
  const float* Wi  = (const float*)d_in[6];
  const float* Wib = (const float*)d_in[7];
  const float* Wc  = (const float*)d_in[8];
  const float* Wcb = (const float*)d_in[9];
  const float* Wow = (const float*)d_in[10];
  const float* Wob = (const float*)d_in[11];
  float* out = (float*)d_out;

  char* ws = (char*)d_ws;
  uint64_t* part0 = (uint64_t*)(ws + 4096);            // 256*8B
  uint64_t* part1 = (uint64_t*)(ws + 8192);
  uint64_t* hh0   = (uint64_t*)(ws + 12288);           // 2048*8B = 16 KB
  uint64_t* hh1   = (uint64_t*)(ws + 12288 + 16384);
  // zero all tags each launch (epochs 1..256; 0 == invalid)
  (void)hipMemsetAsync(ws + 4096, 0, 40960, stream);

  lstm<<<NBLK, TPB, 0, stream>>>(ctx,u,l1w,l1b,Wf,Wfb,Wi,Wib,Wc,Wcb,Wow,Wob,
                                 hh0,hh1,part0,part1,out);
}